// Round 2
// baseline (876.849 us; speedup 1.0000x reference)
//
#include <hip/hip_runtime.h>

// Correlation cost volume: B=4, C=256, H=W=192, MAX_DISP=4 -> 81 displacements.
// out[b, dy*9+dx, y, x] = (1/C) * sum_c F[b,c,y,x] * Spad[b,c,y+dy-4,x+dx-4]
// R2: double-buffered LDS + register prefetch, 1 barrier/chunk, hoisted addresses.

#define MAXD 4
#define WINW 9
#define NDISP 81

constexpr int B_ = 4, C_ = 256, H_ = 192, W_ = 192;
constexpr int TH = 4;                    // output rows per block
constexpr int TW = 64;                   // output cols per block
constexpr int CC = 8;                    // channels staged per chunk
constexpr int NCHUNK = C_ / CC;          // 32
constexpr int SROWS = TH + 2 * MAXD;     // 12
constexpr int SCOLS = TW + 2 * MAXD;     // 72
constexpr int F_STRIDE = 68;
constexpr int S_STRIDE = 72;
constexpr int F_CH = TH * F_STRIDE;      // 272
constexpr int S_CH = SROWS * S_STRIDE;   // 864
constexpr int NTHREADS = 576;            // 9 waves: wave id == dy

__global__ __launch_bounds__(NTHREADS)
void corr_kernel(const float* __restrict__ F, const float* __restrict__ S,
                 float* __restrict__ O) {
    __shared__ float ldsF[2][CC * F_CH]; // 2 x 8.7 KB
    __shared__ float ldsS[2][CC * S_CH]; // 2 x 27.6 KB  (total 72.7 KB)

    const int tid  = threadIdx.x;
    const int y0   = blockIdx.x * TH;
    const int x0   = blockIdx.y * TW;
    const int b    = blockIdx.z;
    const int dy   = tid >> 6;           // wave index = dy in [0,9)
    const int lane = tid & 63;
    const int xg   = lane & 15;          // x-group of 4 pixels
    const int yth  = lane >> 4;          // row within tile, [0,4)

    const long planeHW     = (long)H_ * W_;        // 36864
    const long chunkStride = (long)CC * planeHW;
    const float* Fb = F + (long)b * C_ * planeHW;
    const float* Sb = S + (long)b * C_ * planeHW;

    // ---- loop-invariant staging descriptors ----
    // F: 512 float4 per chunk, threads 0..511
    const bool fval = tid < CC * TH * (TW / 4);
    const int  fcc  = tid >> 6;
    const int  frem = tid & 63;
    const int  fyr  = frem >> 4;
    const int  fcg  = frem & 15;
    const float* fptr = Fb + (long)fcc * planeHW + (long)(y0 + fyr) * W_ + x0 + 4 * fcg;
    const int  fldso = fcc * F_CH + fyr * F_STRIDE + 4 * fcg;

    // S: 1728 float4 per chunk = 3 per thread
    const float* sptr[3];
    int  sldso[3];
    bool sval[3];
    #pragma unroll
    for (int k = 0; k < 3; ++k) {
        int i   = tid + k * NTHREADS;
        int cc  = i / (SROWS * (SCOLS / 4));          // /216
        int rem = i - cc * (SROWS * (SCOLS / 4));
        int r   = rem / (SCOLS / 4);                  // /18
        int cg  = rem - r * (SCOLS / 4);
        int ys  = y0 - MAXD + r;
        int xs  = x0 - MAXD + 4 * cg;
        sval[k]  = ((unsigned)ys < (unsigned)H_) && ((unsigned)xs <= (unsigned)(W_ - 4));
        sptr[k]  = Sb + (long)cc * planeHW + (long)ys * W_ + xs;
        sldso[k] = cc * S_CH + r * S_STRIDE + 4 * cg;
    }

    float acc[WINW][4];
    #pragma unroll
    for (int dx = 0; dx < WINW; ++dx)
        #pragma unroll
        for (int j = 0; j < 4; ++j) acc[dx][j] = 0.f;

    // ---- prologue: stage chunk 0 into buffer 0 ----
    {
        if (fval) *(float4*)(&ldsF[0][fldso]) = *(const float4*)fptr;
        #pragma unroll
        for (int k = 0; k < 3; ++k) {
            float4 v = make_float4(0.f, 0.f, 0.f, 0.f);
            if (sval[k]) v = *(const float4*)sptr[k];
            *(float4*)(&ldsS[0][sldso[k]]) = v;
        }
    }
    __syncthreads();

    for (int ch = 0; ch < NCHUNK; ++ch) {
        const int cur = ch & 1;
        const int nxt = cur ^ 1;

        // ---- issue next chunk's global loads (latency overlapped w/ compute) ----
        float4 fx = make_float4(0.f, 0.f, 0.f, 0.f);
        float4 sx[3];
        #pragma unroll
        for (int k = 0; k < 3; ++k) sx[k] = make_float4(0.f, 0.f, 0.f, 0.f);
        if (ch + 1 < NCHUNK) {
            const long off = (long)(ch + 1) * chunkStride;
            if (fval) fx = *(const float4*)(fptr + off);
            #pragma unroll
            for (int k = 0; k < 3; ++k)
                if (sval[k]) sx[k] = *(const float4*)(sptr[k] + off);
        }

        // ---- compute from buffer `cur` ----
        #pragma unroll
        for (int cc = 0; cc < CC; ++cc) {
            const float4 f = *(const float4*)(&ldsF[cur][cc * F_CH + yth * F_STRIDE + 4 * xg]);
            const int sb = cc * S_CH + (yth + dy) * S_STRIDE + 4 * xg;
            const float4 w0 = *(const float4*)(&ldsS[cur][sb]);
            const float4 w1 = *(const float4*)(&ldsS[cur][sb + 4]);
            const float4 w2 = *(const float4*)(&ldsS[cur][sb + 8]);
            const float w[12] = {w0.x, w0.y, w0.z, w0.w,
                                 w1.x, w1.y, w1.z, w1.w,
                                 w2.x, w2.y, w2.z, w2.w};
            #pragma unroll
            for (int dx = 0; dx < WINW; ++dx) {
                acc[dx][0] += f.x * w[dx];
                acc[dx][1] += f.y * w[dx + 1];
                acc[dx][2] += f.z * w[dx + 2];
                acc[dx][3] += f.w * w[dx + 3];
            }
        }

        // ---- write prefetched regs into the other buffer ----
        if (ch + 1 < NCHUNK) {
            if (fval) *(float4*)(&ldsF[nxt][fldso]) = fx;
            #pragma unroll
            for (int k = 0; k < 3; ++k)
                *(float4*)(&ldsS[nxt][sldso[k]]) = sx[k];
        }
        __syncthreads();   // writes visible AND all compute on `cur` finished
    }

    // ---- epilogue: 9 coalesced float4 stores per thread ----
    const float scale = 1.0f / (float)C_;
    #pragma unroll
    for (int dx = 0; dx < WINW; ++dx) {
        float4 o;
        o.x = acc[dx][0] * scale;
        o.y = acc[dx][1] * scale;
        o.z = acc[dx][2] * scale;
        o.w = acc[dx][3] * scale;
        const int d = dy * WINW + dx;
        float* dst = O + ((long)(b * NDISP + d) * H_ + (y0 + yth)) * W_ + x0 + 4 * xg;
        *(float4*)dst = o;
    }
}

extern "C" void kernel_launch(void* const* d_in, const int* in_sizes, int n_in,
                              void* d_out, int out_size, void* d_ws, size_t ws_size,
                              hipStream_t stream) {
    const float* F = (const float*)d_in[0];
    const float* S = (const float*)d_in[1];
    float* O = (float*)d_out;
    dim3 grid(H_ / TH, W_ / TW, B_);   // 48 x 3 x 4 = 576 blocks
    dim3 block(NTHREADS);
    corr_kernel<<<grid, block, 0, stream>>>(F, S, O);
}

// Round 3
// 639.028 us; speedup vs baseline: 1.3722x; 1.3722x over previous
//
#include <hip/hip_runtime.h>

// Correlation cost volume: B=4, C=256, H=W=192, MAX_DISP=4 -> 81 displacements.
// out[b, dy*9+dx, y, x] = (1/C) * sum_c F[b,c,y,x] * Spad[b,c,y+dy-4,x+dx-4]
// R3: S staged via async global_load_lds (dbuf, 1 barrier/chunk, conflict-free
//     stride 44); F read direct global->reg (L1-served); zero-page for halo.

#define MAXD 4
#define WINW 9
#define NDISP 81

constexpr int B_ = 4, C_ = 256, H_ = 192, W_ = 192;
constexpr int TH = 8;                    // output rows per block
constexpr int TW = 32;                   // output cols per block
constexpr int CC = 8;                    // channels per chunk
constexpr int NCHUNK = C_ / CC;          // 32
constexpr int SROWS = TH + 2 * MAXD;     // 16
constexpr int SGRP = 11;                 // float4 groups per row (10 data + 1 pad)
constexpr int S_STRIDE = 4 * SGRP;       // 44 floats; 11 % 8 == 3 -> bank spread
constexpr int S_CH_F4 = SROWS * SGRP;    // 176 float4 per channel
constexpr int S_F4 = CC * S_CH_F4;       // 1408 float4 per chunk
constexpr int S_CH = SROWS * S_STRIDE;   // 704 floats
constexpr int NTHREADS = 576;            // 9 waves; wave id == dy
constexpr int NSTG = 3;                  // ceil(1408 / 576) staging slots/thread

__device__ __forceinline__ void async_f4(const float* g, float* l) {
    __builtin_amdgcn_global_load_lds(
        (const __attribute__((address_space(1))) void*)g,
        (__attribute__((address_space(3))) void*)l, 16, 0, 0);
}

__global__ void zero_page_kernel(float* p) {
    p[threadIdx.x] = 0.0f;   // 64 floats = 256 B zero page
}

__global__ __launch_bounds__(NTHREADS)
void corr_kernel(const float* __restrict__ F, const float* __restrict__ S,
                 float* __restrict__ O, const float* __restrict__ zpage) {
    __shared__ float ldsS[2][S_F4 * 4];  // 2 x 22 KB = 44 KB

    const int tid  = threadIdx.x;
    const int y0   = blockIdx.x * TH;
    const int x0   = blockIdx.y * TW;
    const int b    = blockIdx.z;
    const int dy   = tid >> 6;           // wave index = dy in [0,9)
    const int lane = tid & 63;
    const int xg   = lane & 7;           // x-group of 4 pixels
    const int yth  = lane >> 3;          // row within tile, [0,8)

    const long planeHW     = (long)H_ * W_;      // 36864
    const long chunkStride = (long)CC * planeHW;
    const float* Fb = F + (long)b * C_ * planeHW;
    const float* Sb = S + (long)b * C_ * planeHW;

    // ---- loop-invariant staging descriptors: NSTG float4 slots per thread ----
    // slot s -> [cc][r][g], LDS offset = s*16B (contiguous, as global_load_lds
    // requires: wave-uniform base + lane*16).
    const float* sgp[NSTG];   // global src for chunk 0 (or zero page)
    long         sstep[NSTG]; // chunkStride if valid else 0 (stay on zero page)
    int          sldso[NSTG]; // LDS float offset
    bool         sact[NSTG];
    #pragma unroll
    for (int k = 0; k < NSTG; ++k) {
        int s   = tid + k * NTHREADS;
        sact[k] = s < S_F4;
        int sc  = sact[k] ? s : 0;
        int cc  = sc / S_CH_F4;
        int rem = sc - cc * S_CH_F4;
        int r   = rem / SGRP;
        int g   = rem - r * SGRP;
        int ys  = y0 - MAXD + r;
        int xs  = x0 - MAXD + 4 * g;
        bool valid = (g < 10) && ((unsigned)ys < (unsigned)H_) &&
                     (xs >= 0) && (xs + 3 < W_);
        sgp[k]   = valid ? (Sb + (long)cc * planeHW + (long)ys * W_ + xs) : zpage;
        sstep[k] = valid ? chunkStride : 0;
        sldso[k] = s * 4;   // floats
    }

    float acc[WINW][4];
    #pragma unroll
    for (int dx = 0; dx < WINW; ++dx)
        #pragma unroll
        for (int j = 0; j < 4; ++j) acc[dx][j] = 0.f;

    const float* Frow = Fb + (long)(y0 + yth) * W_ + x0 + 4 * xg;

    // ---- prologue: stage chunk 0 into buffer 0 ----
    #pragma unroll
    for (int k = 0; k < NSTG; ++k)
        if (sact[k]) async_f4(sgp[k], &ldsS[0][sldso[k]]);
    __syncthreads();   // compiler emits vmcnt(0) drain before s_barrier

    for (int ch = 0; ch < NCHUNK; ++ch) {
        const int cur = ch & 1;
        const int nxt = cur ^ 1;

        // ---- issue next chunk's async loads (no registers consumed) ----
        if (ch + 1 < NCHUNK) {
            #pragma unroll
            for (int k = 0; k < NSTG; ++k)
                if (sact[k])
                    async_f4(sgp[k] + (long)(ch + 1) * sstep[k], &ldsS[nxt][sldso[k]]);
        }

        // ---- compute chunk `ch` from buffer `cur` ----
        const float* fch = Frow + (long)ch * chunkStride;
        #pragma unroll
        for (int cc = 0; cc < CC; ++cc) {
            const float4 f = *(const float4*)(fch + (long)cc * planeHW);
            // S window: tile row r = yth + dy, words 4*xg .. 4*xg+11
            const int sb = cc * S_CH + (yth + dy) * S_STRIDE + 4 * xg;
            const float4 w0 = *(const float4*)(&ldsS[cur][sb]);
            const float4 w1 = *(const float4*)(&ldsS[cur][sb + 4]);
            const float4 w2 = *(const float4*)(&ldsS[cur][sb + 8]);
            const float w[12] = {w0.x, w0.y, w0.z, w0.w,
                                 w1.x, w1.y, w1.z, w1.w,
                                 w2.x, w2.y, w2.z, w2.w};
            #pragma unroll
            for (int dx = 0; dx < WINW; ++dx) {
                acc[dx][0] += f.x * w[dx];
                acc[dx][1] += f.y * w[dx + 1];
                acc[dx][2] += f.z * w[dx + 2];
                acc[dx][3] += f.w * w[dx + 3];
            }
        }
        __syncthreads();   // all compute on cur done AND next loads drained
    }

    // ---- epilogue: 9 coalesced float4 stores per thread ----
    const float scale = 1.0f / (float)C_;
    #pragma unroll
    for (int dx = 0; dx < WINW; ++dx) {
        float4 o;
        o.x = acc[dx][0] * scale;
        o.y = acc[dx][1] * scale;
        o.z = acc[dx][2] * scale;
        o.w = acc[dx][3] * scale;
        const int d = dy * WINW + dx;
        float* dst = O + ((long)(b * NDISP + d) * H_ + (y0 + yth)) * W_ + x0 + 4 * xg;
        *(float4*)dst = o;
    }
}

extern "C" void kernel_launch(void* const* d_in, const int* in_sizes, int n_in,
                              void* d_out, int out_size, void* d_ws, size_t ws_size,
                              hipStream_t stream) {
    const float* F = (const float*)d_in[0];
    const float* S = (const float*)d_in[1];
    float* O  = (float*)d_out;
    float* zp = (float*)d_ws;            // 256 B zero page (re-zeroed every call)
    zero_page_kernel<<<1, 64, 0, stream>>>(zp);
    dim3 grid(H_ / TH, W_ / TW, B_);     // 24 x 6 x 4 = 576 blocks
    corr_kernel<<<grid, dim3(NTHREADS), 0, stream>>>(F, S, O, zp);
}